// Round 9
// baseline (89.900 us; speedup 1.0000x reference)
//
#include <hip/hip_runtime.h>

#define Hc     512
#define Wc     512
#define OH     506
#define OW     506
#define NPIX   (Hc * Wc)
#define BATCH  64
#define CHUNKS 16

#define BH     8                           // output rows per band
#define NBAND  64                          // 63*8=504, band 63 covers 504-505
#define NW     3                           // waves per image-row span
#define WPB    4                           // waves per block
#define GYD    (NBAND / WPB)               // 16
#define NPART  (BATCH * NBAND * NW)        // 12288

typedef float f32x2 __attribute__((ext_vector_type(2)));
typedef float f32x4 __attribute__((ext_vector_type(4)));

// ---------------- Kernel 1: per-(sample,chunk) min/max partials -------------
__global__ __launch_bounds__(256) void mm_part_kernel(
    const float* __restrict__ X, const float* __restrict__ Y,
    float* __restrict__ part)
{
    int blk = blockIdx.x;            // 0 .. BATCH*CHUNKS-1
    int b   = blk >> 4;
    int ch  = blk & 15;
    size_t base = (size_t)b * NPIX + (size_t)ch * (NPIX / CHUNKS);
    const float4* x4 = (const float4*)(X + base);
    const float4* y4 = (const float4*)(Y + base);
    const int n4 = (NPIX / CHUNKS) / 4;   // 4096

    float mn = 1e38f, mx = -1e38f;
    for (int i = threadIdx.x; i < n4; i += 256) {
        float4 a = x4[i];
        float4 c = y4[i];
        mn = fminf(mn, fminf(fminf(a.x, a.y), fminf(a.z, a.w)));
        mx = fmaxf(mx, fmaxf(fmaxf(a.x, a.y), fmaxf(a.z, a.w)));
        mn = fminf(mn, fminf(fminf(c.x, c.y), fminf(c.z, c.w)));
        mx = fmaxf(mx, fmaxf(fmaxf(c.x, c.y), fmaxf(c.z, c.w)));
    }
    #pragma unroll
    for (int off = 1; off < 64; off <<= 1) {
        mn = fminf(mn, __shfl_xor(mn, off, 64));
        mx = fmaxf(mx, __shfl_xor(mx, off, 64));
    }
    __shared__ float smn[4], smx[4];
    int lane = threadIdx.x & 63, wid = threadIdx.x >> 6;
    if (lane == 0) { smn[wid] = mn; smx[wid] = mx; }
    __syncthreads();
    if (threadIdx.x == 0) {
        mn = fminf(fminf(smn[0], smn[1]), fminf(smn[2], smn[3]));
        mx = fmaxf(fmaxf(smx[0], smx[1]), fmaxf(smx[2], smx[3]));
        part[2 * blk]     = mn;
        part[2 * blk + 1] = mx;
    }
}

// ---------------- Kernel 2: fold chunk partials -> C1, C2 per sample --------
__global__ void mm_final_kernel(const float* __restrict__ part,
                                float* __restrict__ c12)
{
    int b = threadIdx.x;
    if (b < BATCH) {
        float mn = 1e38f, mx = -1e38f;
        #pragma unroll
        for (int ch = 0; ch < CHUNKS; ++ch) {
            mn = fminf(mn, part[2 * (b * CHUNKS + ch)]);
            mx = fmaxf(mx, part[2 * (b * CHUNKS + ch) + 1]);
        }
        float dr = mx - mn;
        float c1 = 0.01f * dr;
        float c2 = 0.03f * dr;
        c12[2 * b]     = c1 * c1;
        c12[2 * b + 1] = c2 * c2;
    }
}

// ---------------- Kernel 3: streaming SSIM (R6 structure, more waves) -------
// Each wave: 4 consecutive cols/lane (f32x4), covers 256 cols; 3 waves span a
// row (bases 0/248/496). Vertical 7-window = running sums + re-load of the
// outgoing row (L2-hot). Horizontal 7-window = prefix-shuffle (4 DS ops/stat).
// No LDS, no barriers, no manual pipelining (compiler schedules best).
__global__ __launch_bounds__(256, 8) void ssim_stream_kernel(
    const float* __restrict__ X, const float* __restrict__ Y,
    const float* __restrict__ c12, float* __restrict__ part)
{
    const int lane  = threadIdx.x & 63;
    const int wid   = threadIdx.x >> 6;
    const int chunk = blockIdx.x;               // 0..2
    const int band  = blockIdx.y * WPB + wid;   // 0..63
    const int img   = blockIdx.z;               // 0..63

    const float C1 = c12[2 * img];
    const float C2 = c12[2 * img + 1];
    const f32x2 C1v = {C1, C1};
    const f32x2 C2v = {C2, C2};
    const f32x2 inv2  = {1.0f / 49.0f, 1.0f / 49.0f};
    const f32x2 covn2 = {49.0f / 48.0f, 49.0f / 48.0f};

    // chunk geometry
    const int cbase  = (chunk == 0) ? 0 : (chunk == 1) ? 248 : 496;
    const int out_lo = (chunk == 0) ? 0 : (chunk == 1) ? 250 : 498;
    const int out_hi = (chunk == 0) ? 249 : (chunk == 1) ? 497 : 505;

    const int col0  = cbase + 4 * lane;             // logical first col
    const int col0c = (col0 < 508) ? col0 : 508;    // clamped, 16B aligned
    f32x2 vm01, vm23;
    {
        float v[4];
        #pragma unroll
        for (int j = 0; j < 4; ++j) {
            int oc = col0 + j;
            v[j] = (oc >= out_lo && oc <= out_hi) ? 1.0f : 0.0f;
        }
        vm01 = (f32x2){v[0], v[1]};
        vm23 = (f32x2){v[2], v[3]};
    }

    const int oy0 = band * BH;
    const int nvalid = (OH - oy0) < BH ? (OH - oy0) : BH;   // 8, or 2 (band 63)

    const float* px = X + (size_t)img * NPIX + col0c;
    const float* py = Y + (size_t)img * NPIX + col0c;

    // packed running vertical sums: [0]=cols 0,1  [1]=cols 2,3
    f32x2 Vx[2]  = {{0,0},{0,0}}, Vy[2]  = {{0,0},{0,0}};
    f32x2 Vxy[2] = {{0,0},{0,0}}, Vss[2] = {{0,0},{0,0}};

    #define VADD(xa, ya)                                                     \
    {                                                                        \
        f32x2 xl = (xa).lo, xh = (xa).hi, yl = (ya).lo, yh = (ya).hi;        \
        Vx[0] += xl; Vx[1] += xh; Vy[0] += yl; Vy[1] += yh;                  \
        Vxy[0] += xl * yl; Vxy[1] += xh * yh;                                \
        Vss[0] += xl * xl + yl * yl; Vss[1] += xh * xh + yh * yh;            \
    }
    #define VSUB(xa, ya)                                                     \
    {                                                                        \
        f32x2 xl = (xa).lo, xh = (xa).hi, yl = (ya).lo, yh = (ya).hi;        \
        Vx[0] -= xl; Vx[1] -= xh; Vy[0] -= yl; Vy[1] -= yh;                  \
        Vxy[0] -= xl * yl; Vxy[1] -= xh * yh;                                \
        Vss[0] -= xl * xl + yl * yl; Vss[1] -= xh * xh + yh * yh;            \
    }

    // prologue: accumulate rows oy0..oy0+5 (max 509, no clamp)
    #pragma unroll
    for (int k = 0; k < 6; ++k) {
        f32x4 xa = *(const f32x4*)(px + (size_t)(oy0 + k) * Wc);
        f32x4 ya = *(const f32x4*)(py + (size_t)(oy0 + k) * Wc);
        VADD(xa, ya)
    }

    f32x2 acc2 = {0.f, 0.f};

    // horizontal 7-window via prefix-shuffles: 4 DS ops per stat
    #define H7(V, W0, W1, W2, W3)                                            \
    {                                                                        \
        float v0 = V[0].x, v1 = V[0].y, v2 = V[1].x, v3 = V[1].y;            \
        float t01 = v0 + v1, u23 = v2 + v3;                                  \
        float P3 = t01 + v2, P4 = t01 + u23;                                 \
        float A3 = __shfl_down(P3, 1, 64);                                   \
        float A4 = __shfl_down(P4, 1, 64);                                   \
        float B1 = __shfl_down(v0, 2, 64);                                   \
        float B2 = __shfl_down(t01, 2, 64);                                  \
        float cc = u23 + A4;                                                 \
        W0 = P4 + A3;                                                        \
        W1 = cc + v1;                                                        \
        W2 = cc + B1;                                                        \
        W3 = (v3 + A4) + B2;                                                 \
    }

    #define SSIM2(wx, wy, wp, ws, vmv)                                       \
    {                                                                        \
        f32x2 ux   = wx * inv2;                                              \
        f32x2 uy   = wy * inv2;                                              \
        f32x2 uxuy = ux * uy;                                                \
        f32x2 u2   = ux * ux + uy * uy;                                      \
        f32x2 vxy  = (wp * inv2 - uxuy) * covn2;                             \
        f32x2 vss  = (ws * inv2 - u2) * covn2;                               \
        f32x2 A1   = uxuy + uxuy + C1v;                                      \
        f32x2 A2   = vxy + vxy + C2v;                                        \
        f32x2 B1   = u2 + C1v;                                               \
        f32x2 B2   = vss + C2v;                                              \
        f32x2 den  = B1 * B2;                                                \
        f32x2 num  = A1 * A2;                                                \
        f32x2 rv   = {__builtin_amdgcn_rcpf(den.x),                          \
                      __builtin_amdgcn_rcpf(den.y)};                         \
        acc2 += num * rv * vmv;                                              \
    }

    // running row pointers (strength-reduced addresses)
    const float* pxi = px + (size_t)(oy0 + 6) * Wc;
    const float* pyi = py + (size_t)(oy0 + 6) * Wc;
    const float* pxo = px + (size_t)oy0 * Wc;
    const float* pyo = py + (size_t)oy0 * Wc;

    #pragma unroll 2
    for (int tt = 0; tt < nvalid; ++tt) {
        f32x4 xi = *(const f32x4*)pxi; pxi += Wc;
        f32x4 yi = *(const f32x4*)pyi; pyi += Wc;
        VADD(xi, yi)
        float Wx0, Wx1, Wx2, Wx3;  H7(Vx,  Wx0, Wx1, Wx2, Wx3)
        float Wy0, Wy1, Wy2, Wy3;  H7(Vy,  Wy0, Wy1, Wy2, Wy3)
        float Wp0, Wp1, Wp2, Wp3;  H7(Vxy, Wp0, Wp1, Wp2, Wp3)
        float Ws0, Ws1, Ws2, Ws3;  H7(Vss, Ws0, Ws1, Ws2, Ws3)
        f32x2 wx01 = {Wx0, Wx1}, wx23 = {Wx2, Wx3};
        f32x2 wy01 = {Wy0, Wy1}, wy23 = {Wy2, Wy3};
        f32x2 wp01 = {Wp0, Wp1}, wp23 = {Wp2, Wp3};
        f32x2 ws01 = {Ws0, Ws1}, ws23 = {Ws2, Ws3};
        SSIM2(wx01, wy01, wp01, ws01, vm01)
        SSIM2(wx23, wy23, wp23, ws23, vm23)
        f32x4 xo = *(const f32x4*)pxo; pxo += Wc;
        f32x4 yo = *(const f32x4*)pyo; pyo += Wc;
        VSUB(xo, yo)
    }

    #undef SSIM2
    #undef H7
    #undef VADD
    #undef VSUB

    float acc = acc2.x + acc2.y;
    // deterministic wave reduce
    #pragma unroll
    for (int off = 1; off < 64; off <<= 1)
        acc += __shfl_xor(acc, off, 64);
    if (lane == 0)
        part[((size_t)img * NBAND + band) * NW + chunk] = acc;
}

// ---------------- Kernel 4: final deterministic f64 reduction ---------------
__global__ __launch_bounds__(1024) void final_reduce_kernel(
    const float* __restrict__ part, float* __restrict__ out)
{
    __shared__ double sd[1024];
    double s = 0.0;
    for (int i = threadIdx.x; i < NPART; i += 1024)
        s += (double)part[i];
    sd[threadIdx.x] = s;
    __syncthreads();
    for (int off = 512; off > 0; off >>= 1) {
        if (threadIdx.x < off) sd[threadIdx.x] += sd[threadIdx.x + off];
        __syncthreads();
    }
    if (threadIdx.x == 0)
        out[0] = (float)(sd[0] / ((double)BATCH * OH * OW));
}

extern "C" void kernel_launch(void* const* d_in, const int* in_sizes, int n_in,
                              void* d_out, int out_size, void* d_ws, size_t ws_size,
                              hipStream_t stream) {
    const float* X = (const float*)d_in[0];
    const float* Y = (const float*)d_in[1];
    float* out = (float*)d_out;
    float* ws  = (float*)d_ws;

    float* mmpart = ws;                   // 2 * BATCH * CHUNKS = 2048 floats
    float* c12    = ws + 2048;            // 2 * BATCH = 128 floats
    float* part   = ws + 2048 + 128;      // NPART = 12288 floats

    mm_part_kernel<<<BATCH * CHUNKS, 256, 0, stream>>>(X, Y, mmpart);
    mm_final_kernel<<<1, 64, 0, stream>>>(mmpart, c12);
    dim3 grid(NW, GYD, BATCH);
    ssim_stream_kernel<<<grid, 64 * WPB, 0, stream>>>(X, Y, c12, part);
    final_reduce_kernel<<<1, 1024, 0, stream>>>(part, out);
}

// Round 10
// 84.089 us; speedup vs baseline: 1.0691x; 1.0691x over previous
//
#include <hip/hip_runtime.h>

#define Hc     512
#define Wc     512
#define OH     506
#define OW     506
#define NPIX   (Hc * Wc)
#define BATCH  64
#define CHUNKS 16

#define BH     8                           // output rows per band
#define NBAND  64                          // 63*8=504, band 63 covers 504-505
#define NW     3                           // col-chunks (strips) per image row
#define WPB    4                           // waves (bands) per block
#define BLK_PER_STRIP (NBAND / WPB)        // 16
#define NSTRIP (BATCH * NW)                // 192
#define NBLK   (NSTRIP * BLK_PER_STRIP)    // 3072  (3072 % 8 == 0 -> bijective)
#define STRIPS_PER_XCD (NSTRIP / 8)        // 24
#define NPART  NBLK                        // one partial per block

typedef float f32x2 __attribute__((ext_vector_type(2)));
typedef float f32x4 __attribute__((ext_vector_type(4)));

// ---------------- Kernel 1: per-(sample,chunk) min/max partials -------------
__global__ __launch_bounds__(256) void mm_part_kernel(
    const float* __restrict__ X, const float* __restrict__ Y,
    float* __restrict__ part)
{
    int blk = blockIdx.x;            // 0 .. BATCH*CHUNKS-1
    int b   = blk >> 4;
    int ch  = blk & 15;
    size_t base = (size_t)b * NPIX + (size_t)ch * (NPIX / CHUNKS);
    const float4* x4 = (const float4*)(X + base);
    const float4* y4 = (const float4*)(Y + base);
    const int n4 = (NPIX / CHUNKS) / 4;   // 4096

    float mn = 1e38f, mx = -1e38f;
    for (int i = threadIdx.x; i < n4; i += 256) {
        float4 a = x4[i];
        float4 c = y4[i];
        mn = fminf(mn, fminf(fminf(a.x, a.y), fminf(a.z, a.w)));
        mx = fmaxf(mx, fmaxf(fmaxf(a.x, a.y), fmaxf(a.z, a.w)));
        mn = fminf(mn, fminf(fminf(c.x, c.y), fminf(c.z, c.w)));
        mx = fmaxf(mx, fmaxf(fmaxf(c.x, c.y), fmaxf(c.z, c.w)));
    }
    #pragma unroll
    for (int off = 1; off < 64; off <<= 1) {
        mn = fminf(mn, __shfl_xor(mn, off, 64));
        mx = fmaxf(mx, __shfl_xor(mx, off, 64));
    }
    __shared__ float smn[4], smx[4];
    int lane = threadIdx.x & 63, wid = threadIdx.x >> 6;
    if (lane == 0) { smn[wid] = mn; smx[wid] = mx; }
    __syncthreads();
    if (threadIdx.x == 0) {
        mn = fminf(fminf(smn[0], smn[1]), fminf(smn[2], smn[3]));
        mx = fmaxf(fmaxf(smx[0], smx[1]), fmaxf(smx[2], smx[3]));
        part[2 * blk]     = mn;
        part[2 * blk + 1] = mx;
    }
}

// ---------------- Kernel 2: fold chunk partials -> C1, C2 per sample --------
__global__ void mm_final_kernel(const float* __restrict__ part,
                                float* __restrict__ c12)
{
    int b = threadIdx.x;
    if (b < BATCH) {
        float mn = 1e38f, mx = -1e38f;
        #pragma unroll
        for (int ch = 0; ch < CHUNKS; ++ch) {
            mn = fminf(mn, part[2 * (b * CHUNKS + ch)]);
            mx = fmaxf(mx, part[2 * (b * CHUNKS + ch) + 1]);
        }
        float dr = mx - mn;
        float c1 = 0.01f * dr;
        float c2 = 0.03f * dr;
        c12[2 * b]     = c1 * c1;
        c12[2 * b + 1] = c2 * c2;
    }
}

// ---------------- Kernel 3: streaming SSIM, XCD-affine block mapping --------
// Body identical to R9 (verified). Mapping: xcd = lin%8 owns 24 whole
// (img,chunk) strips; consecutive slots = consecutive band-blocks of one
// strip, so the 6-row band overlaps are served by the XCD's own L2.
__global__ __launch_bounds__(256, 8) void ssim_stream_kernel(
    const float* __restrict__ X, const float* __restrict__ Y,
    const float* __restrict__ c12, float* __restrict__ part)
{
    const int lane = threadIdx.x & 63;
    const int wid  = threadIdx.x >> 6;

    // XCD-affine swizzle (bijective: NBLK % 8 == 0)
    const int lin   = blockIdx.x;            // 0..3071
    const int xcd   = lin & 7;
    const int slot  = lin >> 3;              // 0..383
    const int strip_local = slot >> 4;       // 0..23
    const int blk   = slot & 15;             // band-block within strip
    const int strip = xcd * STRIPS_PER_XCD + strip_local;   // 0..191
    const int img   = strip / NW;
    const int chunk = strip - img * NW;      // 0..2
    const int band  = blk * WPB + wid;       // 0..63

    const float C1 = c12[2 * img];
    const float C2 = c12[2 * img + 1];
    const f32x2 C1v = {C1, C1};
    const f32x2 C2v = {C2, C2};
    const f32x2 inv2  = {1.0f / 49.0f, 1.0f / 49.0f};
    const f32x2 covn2 = {49.0f / 48.0f, 49.0f / 48.0f};

    // chunk geometry
    const int cbase  = (chunk == 0) ? 0 : (chunk == 1) ? 248 : 496;
    const int out_lo = (chunk == 0) ? 0 : (chunk == 1) ? 250 : 498;
    const int out_hi = (chunk == 0) ? 249 : (chunk == 1) ? 497 : 505;

    const int col0  = cbase + 4 * lane;             // logical first col
    const int col0c = (col0 < 508) ? col0 : 508;    // clamped, 16B aligned
    f32x2 vm01, vm23;
    {
        float v[4];
        #pragma unroll
        for (int j = 0; j < 4; ++j) {
            int oc = col0 + j;
            v[j] = (oc >= out_lo && oc <= out_hi) ? 1.0f : 0.0f;
        }
        vm01 = (f32x2){v[0], v[1]};
        vm23 = (f32x2){v[2], v[3]};
    }

    const int oy0 = band * BH;
    const int nvalid = (OH - oy0) < BH ? (OH - oy0) : BH;   // 8, or 2 (band 63)

    const float* px = X + (size_t)img * NPIX + col0c;
    const float* py = Y + (size_t)img * NPIX + col0c;

    // packed running vertical sums: [0]=cols 0,1  [1]=cols 2,3
    f32x2 Vx[2]  = {{0,0},{0,0}}, Vy[2]  = {{0,0},{0,0}};
    f32x2 Vxy[2] = {{0,0},{0,0}}, Vss[2] = {{0,0},{0,0}};

    #define VADD(xa, ya)                                                     \
    {                                                                        \
        f32x2 xl = (xa).lo, xh = (xa).hi, yl = (ya).lo, yh = (ya).hi;        \
        Vx[0] += xl; Vx[1] += xh; Vy[0] += yl; Vy[1] += yh;                  \
        Vxy[0] += xl * yl; Vxy[1] += xh * yh;                                \
        Vss[0] += xl * xl + yl * yl; Vss[1] += xh * xh + yh * yh;            \
    }
    #define VSUB(xa, ya)                                                     \
    {                                                                        \
        f32x2 xl = (xa).lo, xh = (xa).hi, yl = (ya).lo, yh = (ya).hi;        \
        Vx[0] -= xl; Vx[1] -= xh; Vy[0] -= yl; Vy[1] -= yh;                  \
        Vxy[0] -= xl * yl; Vxy[1] -= xh * yh;                                \
        Vss[0] -= xl * xl + yl * yl; Vss[1] -= xh * xh + yh * yh;            \
    }

    // prologue: accumulate rows oy0..oy0+5 (max 509, no clamp)
    #pragma unroll
    for (int k = 0; k < 6; ++k) {
        f32x4 xa = *(const f32x4*)(px + (size_t)(oy0 + k) * Wc);
        f32x4 ya = *(const f32x4*)(py + (size_t)(oy0 + k) * Wc);
        VADD(xa, ya)
    }

    f32x2 acc2 = {0.f, 0.f};

    // horizontal 7-window via prefix-shuffles: 4 DS ops per stat
    #define H7(V, W0, W1, W2, W3)                                            \
    {                                                                        \
        float v0 = V[0].x, v1 = V[0].y, v2 = V[1].x, v3 = V[1].y;            \
        float t01 = v0 + v1, u23 = v2 + v3;                                  \
        float P3 = t01 + v2, P4 = t01 + u23;                                 \
        float A3 = __shfl_down(P3, 1, 64);                                   \
        float A4 = __shfl_down(P4, 1, 64);                                   \
        float B1 = __shfl_down(v0, 2, 64);                                   \
        float B2 = __shfl_down(t01, 2, 64);                                  \
        float cc = u23 + A4;                                                 \
        W0 = P4 + A3;                                                        \
        W1 = cc + v1;                                                        \
        W2 = cc + B1;                                                        \
        W3 = (v3 + A4) + B2;                                                 \
    }

    #define SSIM2(wx, wy, wp, ws, vmv)                                       \
    {                                                                        \
        f32x2 ux   = wx * inv2;                                              \
        f32x2 uy   = wy * inv2;                                              \
        f32x2 uxuy = ux * uy;                                                \
        f32x2 u2   = ux * ux + uy * uy;                                      \
        f32x2 vxy  = (wp * inv2 - uxuy) * covn2;                             \
        f32x2 vss  = (ws * inv2 - u2) * covn2;                               \
        f32x2 A1   = uxuy + uxuy + C1v;                                      \
        f32x2 A2   = vxy + vxy + C2v;                                        \
        f32x2 B1   = u2 + C1v;                                               \
        f32x2 B2   = vss + C2v;                                              \
        f32x2 den  = B1 * B2;                                                \
        f32x2 num  = A1 * A2;                                                \
        f32x2 rv   = {__builtin_amdgcn_rcpf(den.x),                          \
                      __builtin_amdgcn_rcpf(den.y)};                         \
        acc2 += num * rv * vmv;                                              \
    }

    // running row pointers (strength-reduced addresses)
    const float* pxi = px + (size_t)(oy0 + 6) * Wc;
    const float* pyi = py + (size_t)(oy0 + 6) * Wc;
    const float* pxo = px + (size_t)oy0 * Wc;
    const float* pyo = py + (size_t)oy0 * Wc;

    #pragma unroll 2
    for (int tt = 0; tt < nvalid; ++tt) {
        f32x4 xi = *(const f32x4*)pxi; pxi += Wc;
        f32x4 yi = *(const f32x4*)pyi; pyi += Wc;
        VADD(xi, yi)
        float Wx0, Wx1, Wx2, Wx3;  H7(Vx,  Wx0, Wx1, Wx2, Wx3)
        float Wy0, Wy1, Wy2, Wy3;  H7(Vy,  Wy0, Wy1, Wy2, Wy3)
        float Wp0, Wp1, Wp2, Wp3;  H7(Vxy, Wp0, Wp1, Wp2, Wp3)
        float Ws0, Ws1, Ws2, Ws3;  H7(Vss, Ws0, Ws1, Ws2, Ws3)
        f32x2 wx01 = {Wx0, Wx1}, wx23 = {Wx2, Wx3};
        f32x2 wy01 = {Wy0, Wy1}, wy23 = {Wy2, Wy3};
        f32x2 wp01 = {Wp0, Wp1}, wp23 = {Wp2, Wp3};
        f32x2 ws01 = {Ws0, Ws1}, ws23 = {Ws2, Ws3};
        SSIM2(wx01, wy01, wp01, ws01, vm01)
        SSIM2(wx23, wy23, wp23, ws23, vm23)
        f32x4 xo = *(const f32x4*)pxo; pxo += Wc;
        f32x4 yo = *(const f32x4*)pyo; pyo += Wc;
        VSUB(xo, yo)
    }

    #undef SSIM2
    #undef H7
    #undef VADD
    #undef VSUB

    float acc = acc2.x + acc2.y;
    // deterministic wave reduce + cross-wave LDS fold (one partial per block)
    #pragma unroll
    for (int off = 1; off < 64; off <<= 1)
        acc += __shfl_xor(acc, off, 64);
    __shared__ float sacc[4];
    if (lane == 0) sacc[wid] = acc;
    __syncthreads();
    if (threadIdx.x == 0)
        part[lin] = (sacc[0] + sacc[1]) + (sacc[2] + sacc[3]);
}

// ---------------- Kernel 4: final deterministic f64 reduction ---------------
__global__ __launch_bounds__(1024) void final_reduce_kernel(
    const float* __restrict__ part, float* __restrict__ out)
{
    __shared__ double sd[1024];
    double s = 0.0;
    for (int i = threadIdx.x; i < NPART; i += 1024)
        s += (double)part[i];
    sd[threadIdx.x] = s;
    __syncthreads();
    for (int off = 512; off > 0; off >>= 1) {
        if (threadIdx.x < off) sd[threadIdx.x] += sd[threadIdx.x + off];
        __syncthreads();
    }
    if (threadIdx.x == 0)
        out[0] = (float)(sd[0] / ((double)BATCH * OH * OW));
}

extern "C" void kernel_launch(void* const* d_in, const int* in_sizes, int n_in,
                              void* d_out, int out_size, void* d_ws, size_t ws_size,
                              hipStream_t stream) {
    const float* X = (const float*)d_in[0];
    const float* Y = (const float*)d_in[1];
    float* out = (float*)d_out;
    float* ws  = (float*)d_ws;

    float* mmpart = ws;                   // 2 * BATCH * CHUNKS = 2048 floats
    float* c12    = ws + 2048;            // 2 * BATCH = 128 floats
    float* part   = ws + 2048 + 128;      // NPART = 3072 floats

    mm_part_kernel<<<BATCH * CHUNKS, 256, 0, stream>>>(X, Y, mmpart);
    mm_final_kernel<<<1, 64, 0, stream>>>(mmpart, c12);
    ssim_stream_kernel<<<NBLK, 64 * WPB, 0, stream>>>(X, Y, c12, part);
    final_reduce_kernel<<<1, 1024, 0, stream>>>(part, out);
}

// Round 11
// 75.350 us; speedup vs baseline: 1.1931x; 1.1160x over previous
//
#include <hip/hip_runtime.h>

#define Hc     512
#define Wc     512
#define OH     506
#define OW     506
#define NPIX   (Hc * Wc)
#define BATCH  64
#define CHUNKS 16

#define BH     16                          // output rows per band
#define NBAND  32                          // 31*16=496, band 31 covers 496-505
#define NW     3                           // col-chunks (strips) per image row
#define WPB    4                           // waves (bands) per block
#define BLK_PER_STRIP (NBAND / WPB)        // 8
#define NSTRIP (BATCH * NW)                // 192
#define NBLK   (NSTRIP * BLK_PER_STRIP)    // 1536  (%8==0 -> bijective swizzle)
#define STRIPS_PER_XCD (NSTRIP / 8)        // 24
#define NPART  NBLK                        // one partial per block

typedef float f32x2 __attribute__((ext_vector_type(2)));
typedef float f32x4 __attribute__((ext_vector_type(4)));

// ---------------- Kernel 1: per-(sample,chunk) min/max partials -------------
__global__ __launch_bounds__(256) void mm_part_kernel(
    const float* __restrict__ X, const float* __restrict__ Y,
    float* __restrict__ part)
{
    int blk = blockIdx.x;            // 0 .. BATCH*CHUNKS-1
    int b   = blk >> 4;
    int ch  = blk & 15;
    size_t base = (size_t)b * NPIX + (size_t)ch * (NPIX / CHUNKS);
    const float4* x4 = (const float4*)(X + base);
    const float4* y4 = (const float4*)(Y + base);
    const int n4 = (NPIX / CHUNKS) / 4;   // 4096

    float mn = 1e38f, mx = -1e38f;
    for (int i = threadIdx.x; i < n4; i += 256) {
        float4 a = x4[i];
        float4 c = y4[i];
        mn = fminf(mn, fminf(fminf(a.x, a.y), fminf(a.z, a.w)));
        mx = fmaxf(mx, fmaxf(fmaxf(a.x, a.y), fmaxf(a.z, a.w)));
        mn = fminf(mn, fminf(fminf(c.x, c.y), fminf(c.z, c.w)));
        mx = fmaxf(mx, fmaxf(fmaxf(c.x, c.y), fmaxf(c.z, c.w)));
    }
    #pragma unroll
    for (int off = 1; off < 64; off <<= 1) {
        mn = fminf(mn, __shfl_xor(mn, off, 64));
        mx = fmaxf(mx, __shfl_xor(mx, off, 64));
    }
    __shared__ float smn[4], smx[4];
    int lane = threadIdx.x & 63, wid = threadIdx.x >> 6;
    if (lane == 0) { smn[wid] = mn; smx[wid] = mx; }
    __syncthreads();
    if (threadIdx.x == 0) {
        mn = fminf(fminf(smn[0], smn[1]), fminf(smn[2], smn[3]));
        mx = fmaxf(fmaxf(smx[0], smx[1]), fmaxf(smx[2], smx[3]));
        part[2 * blk]     = mn;
        part[2 * blk + 1] = mx;
    }
}

// ---------------- Kernel 2: streaming SSIM, XCD-affine, single-round --------
// Body identical to R10 (verified). BH=16: 6 blocks/CU, one residency round.
// mm_final folded in: each block folds its image's 32 chunk partials (L2-hot).
__global__ __launch_bounds__(256, 8) void ssim_stream_kernel(
    const float* __restrict__ X, const float* __restrict__ Y,
    const float* __restrict__ mmpart, float* __restrict__ part)
{
    const int lane = threadIdx.x & 63;
    const int wid  = threadIdx.x >> 6;

    // XCD-affine swizzle (bijective: NBLK % 8 == 0)
    const int lin   = blockIdx.x;            // 0..1535
    const int xcd   = lin & 7;
    const int slot  = lin >> 3;              // 0..191
    const int strip_local = slot >> 3;       // 0..23
    const int blk   = slot & 7;              // band-block within strip
    const int strip = xcd * STRIPS_PER_XCD + strip_local;   // 0..191
    const int img   = strip / NW;
    const int chunk = strip - img * NW;      // 0..2
    const int band  = blk * WPB + wid;       // 0..31

    // fold chunk min/max -> C1, C2 (uniform; L2-hot, hidden under prologue)
    float mn = 1e38f, mx = -1e38f;
    #pragma unroll
    for (int ch = 0; ch < CHUNKS; ++ch) {
        mn = fminf(mn, mmpart[2 * (img * CHUNKS + ch)]);
        mx = fmaxf(mx, mmpart[2 * (img * CHUNKS + ch) + 1]);
    }
    const float dr = mx - mn;
    const float C1 = (0.01f * dr) * (0.01f * dr);
    const float C2 = (0.03f * dr) * (0.03f * dr);
    const f32x2 C1v = {C1, C1};
    const f32x2 C2v = {C2, C2};
    const f32x2 inv2  = {1.0f / 49.0f, 1.0f / 49.0f};
    const f32x2 covn2 = {49.0f / 48.0f, 49.0f / 48.0f};

    // chunk geometry
    const int cbase  = (chunk == 0) ? 0 : (chunk == 1) ? 248 : 496;
    const int out_lo = (chunk == 0) ? 0 : (chunk == 1) ? 250 : 498;
    const int out_hi = (chunk == 0) ? 249 : (chunk == 1) ? 497 : 505;

    const int col0  = cbase + 4 * lane;             // logical first col
    const int col0c = (col0 < 508) ? col0 : 508;    // clamped, 16B aligned
    f32x2 vm01, vm23;
    {
        float v[4];
        #pragma unroll
        for (int j = 0; j < 4; ++j) {
            int oc = col0 + j;
            v[j] = (oc >= out_lo && oc <= out_hi) ? 1.0f : 0.0f;
        }
        vm01 = (f32x2){v[0], v[1]};
        vm23 = (f32x2){v[2], v[3]};
    }

    const int oy0 = band * BH;
    const int nvalid = (OH - oy0) < BH ? (OH - oy0) : BH;   // 16, or 10 (band 31)

    const float* px = X + (size_t)img * NPIX + col0c;
    const float* py = Y + (size_t)img * NPIX + col0c;

    // packed running vertical sums: [0]=cols 0,1  [1]=cols 2,3
    f32x2 Vx[2]  = {{0,0},{0,0}}, Vy[2]  = {{0,0},{0,0}};
    f32x2 Vxy[2] = {{0,0},{0,0}}, Vss[2] = {{0,0},{0,0}};

    #define VADD(xa, ya)                                                     \
    {                                                                        \
        f32x2 xl = (xa).lo, xh = (xa).hi, yl = (ya).lo, yh = (ya).hi;        \
        Vx[0] += xl; Vx[1] += xh; Vy[0] += yl; Vy[1] += yh;                  \
        Vxy[0] += xl * yl; Vxy[1] += xh * yh;                                \
        Vss[0] += xl * xl + yl * yl; Vss[1] += xh * xh + yh * yh;            \
    }
    #define VSUB(xa, ya)                                                     \
    {                                                                        \
        f32x2 xl = (xa).lo, xh = (xa).hi, yl = (ya).lo, yh = (ya).hi;        \
        Vx[0] -= xl; Vx[1] -= xh; Vy[0] -= yl; Vy[1] -= yh;                  \
        Vxy[0] -= xl * yl; Vxy[1] -= xh * yh;                                \
        Vss[0] -= xl * xl + yl * yl; Vss[1] -= xh * xh + yh * yh;            \
    }

    // prologue: accumulate rows oy0..oy0+5 (max 501, no clamp)
    #pragma unroll
    for (int k = 0; k < 6; ++k) {
        f32x4 xa = *(const f32x4*)(px + (size_t)(oy0 + k) * Wc);
        f32x4 ya = *(const f32x4*)(py + (size_t)(oy0 + k) * Wc);
        VADD(xa, ya)
    }

    f32x2 acc2 = {0.f, 0.f};

    // horizontal 7-window via prefix-shuffles: 4 DS ops per stat
    #define H7(V, W0, W1, W2, W3)                                            \
    {                                                                        \
        float v0 = V[0].x, v1 = V[0].y, v2 = V[1].x, v3 = V[1].y;            \
        float t01 = v0 + v1, u23 = v2 + v3;                                  \
        float P3 = t01 + v2, P4 = t01 + u23;                                 \
        float A3 = __shfl_down(P3, 1, 64);                                   \
        float A4 = __shfl_down(P4, 1, 64);                                   \
        float B1 = __shfl_down(v0, 2, 64);                                   \
        float B2 = __shfl_down(t01, 2, 64);                                  \
        float cc = u23 + A4;                                                 \
        W0 = P4 + A3;                                                        \
        W1 = cc + v1;                                                        \
        W2 = cc + B1;                                                        \
        W3 = (v3 + A4) + B2;                                                 \
    }

    #define SSIM2(wx, wy, wp, ws, vmv)                                       \
    {                                                                        \
        f32x2 ux   = wx * inv2;                                              \
        f32x2 uy   = wy * inv2;                                              \
        f32x2 uxuy = ux * uy;                                                \
        f32x2 u2   = ux * ux + uy * uy;                                      \
        f32x2 vxy  = (wp * inv2 - uxuy) * covn2;                             \
        f32x2 vss  = (ws * inv2 - u2) * covn2;                               \
        f32x2 A1   = uxuy + uxuy + C1v;                                      \
        f32x2 A2   = vxy + vxy + C2v;                                        \
        f32x2 B1   = u2 + C1v;                                               \
        f32x2 B2   = vss + C2v;                                              \
        f32x2 den  = B1 * B2;                                                \
        f32x2 num  = A1 * A2;                                                \
        f32x2 rv   = {__builtin_amdgcn_rcpf(den.x),                          \
                      __builtin_amdgcn_rcpf(den.y)};                         \
        acc2 += num * rv * vmv;                                              \
    }

    // running row pointers (strength-reduced addresses)
    const float* pxi = px + (size_t)(oy0 + 6) * Wc;
    const float* pyi = py + (size_t)(oy0 + 6) * Wc;
    const float* pxo = px + (size_t)oy0 * Wc;
    const float* pyo = py + (size_t)oy0 * Wc;

    #pragma unroll 2
    for (int tt = 0; tt < nvalid; ++tt) {
        f32x4 xi = *(const f32x4*)pxi; pxi += Wc;
        f32x4 yi = *(const f32x4*)pyi; pyi += Wc;
        VADD(xi, yi)
        float Wx0, Wx1, Wx2, Wx3;  H7(Vx,  Wx0, Wx1, Wx2, Wx3)
        float Wy0, Wy1, Wy2, Wy3;  H7(Vy,  Wy0, Wy1, Wy2, Wy3)
        float Wp0, Wp1, Wp2, Wp3;  H7(Vxy, Wp0, Wp1, Wp2, Wp3)
        float Ws0, Ws1, Ws2, Ws3;  H7(Vss, Ws0, Ws1, Ws2, Ws3)
        f32x2 wx01 = {Wx0, Wx1}, wx23 = {Wx2, Wx3};
        f32x2 wy01 = {Wy0, Wy1}, wy23 = {Wy2, Wy3};
        f32x2 wp01 = {Wp0, Wp1}, wp23 = {Wp2, Wp3};
        f32x2 ws01 = {Ws0, Ws1}, ws23 = {Ws2, Ws3};
        SSIM2(wx01, wy01, wp01, ws01, vm01)
        SSIM2(wx23, wy23, wp23, ws23, vm23)
        f32x4 xo = *(const f32x4*)pxo; pxo += Wc;
        f32x4 yo = *(const f32x4*)pyo; pyo += Wc;
        VSUB(xo, yo)
    }

    #undef SSIM2
    #undef H7
    #undef VADD
    #undef VSUB

    float acc = acc2.x + acc2.y;
    // deterministic wave reduce + cross-wave LDS fold (one partial per block)
    #pragma unroll
    for (int off = 1; off < 64; off <<= 1)
        acc += __shfl_xor(acc, off, 64);
    __shared__ float sacc[4];
    if (lane == 0) sacc[wid] = acc;
    __syncthreads();
    if (threadIdx.x == 0)
        part[lin] = (sacc[0] + sacc[1]) + (sacc[2] + sacc[3]);
}

// ---------------- Kernel 3: final deterministic f64 reduction ---------------
__global__ __launch_bounds__(1024) void final_reduce_kernel(
    const float* __restrict__ part, float* __restrict__ out)
{
    __shared__ double sd[1024];
    double s = 0.0;
    for (int i = threadIdx.x; i < NPART; i += 1024)
        s += (double)part[i];
    sd[threadIdx.x] = s;
    __syncthreads();
    for (int off = 512; off > 0; off >>= 1) {
        if (threadIdx.x < off) sd[threadIdx.x] += sd[threadIdx.x + off];
        __syncthreads();
    }
    if (threadIdx.x == 0)
        out[0] = (float)(sd[0] / ((double)BATCH * OH * OW));
}

extern "C" void kernel_launch(void* const* d_in, const int* in_sizes, int n_in,
                              void* d_out, int out_size, void* d_ws, size_t ws_size,
                              hipStream_t stream) {
    const float* X = (const float*)d_in[0];
    const float* Y = (const float*)d_in[1];
    float* out = (float*)d_out;
    float* ws  = (float*)d_ws;

    float* mmpart = ws;                   // 2 * BATCH * CHUNKS = 2048 floats
    float* part   = ws + 2048;            // NPART = 1536 floats

    mm_part_kernel<<<BATCH * CHUNKS, 256, 0, stream>>>(X, Y, mmpart);
    ssim_stream_kernel<<<NBLK, 64 * WPB, 0, stream>>>(X, Y, mmpart, part);
    final_reduce_kernel<<<1, 1024, 0, stream>>>(part, out);
}